// Round 10
// baseline (698.664 us; speedup 1.0000x reference)
//
#include <hip/hip_runtime.h>

#define HD 50
#define TT 512
#define BRR 16        // batch rows per block -> 256 blocks = 1/CU
#define TC 32         // x prefetch chunk (timesteps)
#define HS 72         // shorts per h row (144B stride; b128 A-reads bank-balanced)

using bf16x8 = __attribute__((ext_vector_type(8))) short;
using f32x4  = __attribute__((ext_vector_type(4))) float;

__device__ __forceinline__ unsigned short f2bf(float f) {   // RNE float->bf16
    unsigned int u = __float_as_uint(f);
    u += 0x7FFFu + ((u >> 16) & 1u);
    return (unsigned short)(u >> 16);
}
__device__ __forceinline__ float bf2f(unsigned short b) {
    return __uint_as_float(((unsigned int)b) << 16);
}
__device__ __forceinline__ float frcp(float x) { return __builtin_amdgcn_rcpf(x); }
__device__ __forceinline__ float sigf(float x) { return frcp(1.0f + __expf(-x)); }
__device__ __forceinline__ float tanhfast(float x) {
    return 1.0f - 2.0f * frcp(__expf(2.0f * x) + 1.0f);
}

// Phase-staggered tick (overlap matrix pipe with trans/VALU pipe across the
// two wave groups; m114: separate waves' MFMA and VALU co-schedule):
//   phase1: pathA MFMA pre0(n)        || pathB EW: pre1(n-3)->h1(n-3)
//   phase2: pathA EW: pre0(n)->h0(n)  || pathB MFMA pre1(n-2) (acc kept in regs)
// h0 triple-buffered (n%3); h1 SINGLE buffer (write ph1 -> read ph2 same tick);
// acc lives across one barrier per path. Gate-major tiles, in-register EW.
__global__ __launch_bounds__(512, 2) void lstm2_mfma7(
    const float* __restrict__ x,
    const float* __restrict__ Wih0, const float* __restrict__ Whh0,
    const float* __restrict__ bih0, const float* __restrict__ bhh0,
    const float* __restrict__ Wih1, const float* __restrict__ Whh1,
    const float* __restrict__ bih1, const float* __restrict__ bhh1,
    const float* __restrict__ Wfc, const float* __restrict__ bfc,
    float* __restrict__ out)
{
    __shared__ short s_h0hi[3][BRR][HS], s_h0lo[3][BRR][HS]; // k: 0-49 h0, 50-52 x, 53+ 0
    __shared__ short s_h1hi[BRR][HS],    s_h1lo[BRR][HS];    // k: 0-49 h1, 50+ 0
    __shared__ float s_xs[2][BRR][TC*3];

    const int tid  = threadIdx.x;
    const int wid  = tid >> 6;
    const int lane = tid & 63;
    const int lr   = lane & 15;    // B/D column = unit slot
    const int lq   = lane >> 4;    // k-octet / D row-quad
    const int r0   = blockIdx.x * BRR;
    const bool pathA = (wid < 4);
    const int  wsub  = wid & 3;
    const int  u     = lr * 4 + wsub;      // this lane's hidden unit
    const bool valid = (u < HD);

    // ---- weight B-fragments (hi/lo), register-resident; tile tt = gate type ----
    bf16x8 bh[4][4], bl[4][4];
    float bvT[4];
    #pragma unroll
    for (int tt = 0; tt < 4; ++tt) {
        #pragma unroll
        for (int s = 0; s < 4; ++s) { bh[tt][s] = (bf16x8)0; bl[tt][s] = (bf16x8)0; }
        const int g = tt * HD + (valid ? u : 0);     // gate-row in [0,200)
        if (pathA) {
            bvT[tt] = valid ? bih0[g] + bhh0[g] : 0.f;
            #pragma unroll
            for (int s = 0; s < 2; ++s) {
                #pragma unroll
                for (int j = 0; j < 8; ++j) {
                    const int k = s*32 + lq*8 + j;
                    float wv = 0.f;
                    if (valid) {
                        if (k < HD) wv = Whh0[g*HD + k];
                        else if (k < HD+3) wv = Wih0[g*3 + (k-HD)];
                    }
                    const unsigned short hb = f2bf(wv);
                    bh[tt][s][j] = (short)hb;
                    bl[tt][s][j] = (short)f2bf(wv - bf2f(hb));
                }
            }
        } else {
            bvT[tt] = valid ? bih1[g] + bhh1[g] : 0.f;
            #pragma unroll
            for (int s = 0; s < 4; ++s) {
                #pragma unroll
                for (int j = 0; j < 8; ++j) {
                    const int k = s*32 + lq*8 + j;   // 0-63: Wih1 k-space, 64-127: Whh1
                    float wv = 0.f;
                    if (valid) {
                        if (k < HD) wv = Wih1[g*HD + k];
                        else if (k >= 64 && k < 64+HD) wv = Whh1[g*HD + (k-64)];
                    }
                    const unsigned short hb = f2bf(wv);
                    bh[tt][s][j] = (short)hb;
                    bl[tt][s][j] = (short)f2bf(wv - bf2f(hb));
                }
            }
        }
    }

    // ---- per-lane c-state: 4 batch rows (4*lq+j) of unit u ----
    float cst[4] = {0.f, 0.f, 0.f, 0.f};

    // ---- acc carried across barriers ----
    f32x4 accA[4], accB[4];
    #pragma unroll
    for (int tt = 0; tt < 4; ++tt) { accA[tt] = (f32x4){0,0,0,0}; accB[tt] = (f32x4){0,0,0,0}; }

    // ---- x duty: tids 0-47 (subset of wave 0, pathA) ----
    const bool xth = (tid < 48);
    const int  xr  = tid / 3, xd = tid % 3;

    // ---- init LDS ----
    for (int p = tid; p < 3*BRR*HS; p += 512) {
        ((short*)s_h0hi)[p] = 0; ((short*)s_h0lo)[p] = 0;
    }
    for (int p = tid; p < BRR*HS; p += 512) {
        ((short*)s_h1hi)[p] = 0; ((short*)s_h1lo)[p] = 0;
    }
    for (int p = tid; p < BRR*TC*3; p += 512) {       // stage x chunk 0
        const int rr = p / (TC*3), q = p % (TC*3);
        s_xs[0][rr][q] = x[(size_t)(r0+rr)*(TT*3) + q];
    }
    __syncthreads();
    if (xth) {                                        // x(0) -> h0 buf 2 (= ridx at n=0)
        const float xv = s_xs[0][xr][xd];
        const unsigned short xh = f2bf(xv);
        s_h0hi[2][xr][HD+xd] = (short)xh;
        s_h0lo[2][xr][HD+xd] = (short)f2bf(xv - bf2f(xh));
    }
    __syncthreads();

    // ================= main loop: TT+3 ticks, TWO barriers each =================
    for (int n = 0; n <= TT + 2; ++n) {
        const int ridx = (n + 2) % 3;                  // h0(n-1)
        const int widx = n % 3;                        // h0(n)
        const int bidx = (n + 1) % 3;                  // h0(n-2)

        // ---------- phase 1: MFMA_A(n) || EW_B(n-3) ----------
        if (pathA) {
            if (n < TT) {                              // pre0(n) = [h0(n-1)|x(n)] @ W0
                const char* hb0 = (const char*)&s_h0hi[ridx][0][0];
                const char* lb0 = (const char*)&s_h0lo[ridx][0][0];
                bf16x8 ah[2], al[2];
                #pragma unroll
                for (int s = 0; s < 2; ++s) {
                    const int off = lr*(2*HS) + s*64 + lq*16;
                    ah[s] = *(const bf16x8*)(hb0 + off);
                    al[s] = *(const bf16x8*)(lb0 + off);
                }
                #pragma unroll
                for (int tt = 0; tt < 4; ++tt) { const float b = bvT[tt]; accA[tt] = (f32x4){b,b,b,b}; }
                #pragma unroll
                for (int s = 0; s < 2; ++s) {
                    #pragma unroll
                    for (int tt = 0; tt < 4; ++tt)
                        accA[tt] = __builtin_amdgcn_mfma_f32_16x16x32_bf16(ah[s], bh[tt][s], accA[tt], 0,0,0);
                    #pragma unroll
                    for (int tt = 0; tt < 4; ++tt)
                        accA[tt] = __builtin_amdgcn_mfma_f32_16x16x32_bf16(al[s], bh[tt][s], accA[tt], 0,0,0);
                    #pragma unroll
                    for (int tt = 0; tt < 4; ++tt)
                        accA[tt] = __builtin_amdgcn_mfma_f32_16x16x32_bf16(ah[s], bl[tt][s], accA[tt], 0,0,0);
                }
            }
        } else {
            if (n >= 3 && valid) {                     // EW_B: pre1(n-3) -> h1(n-3)
                #pragma unroll
                for (int j = 0; j < 4; ++j) {
                    const float iv = sigf(accB[0][j]);
                    const float fv = sigf(accB[1][j]);
                    const float gv = tanhfast(accB[2][j]);
                    const float ov = sigf(accB[3][j]);
                    const float c  = fv*cst[j] + iv*gv;
                    cst[j] = c;
                    const float h  = ov*tanhfast(c);
                    const unsigned short hb2 = f2bf(h);
                    s_h1hi[lq*4+j][u] = (short)hb2;
                    s_h1lo[lq*4+j][u] = (short)f2bf(h - bf2f(hb2));
                }
            }
        }
        __syncthreads();

        // ---------- phase 2: EW_A(n) + x-duty || MFMA_B(n-2) ----------
        if (pathA) {
            if (n < TT && valid) {                     // EW_A: pre0(n) -> h0(n) in buf[widx]
                #pragma unroll
                for (int j = 0; j < 4; ++j) {
                    const float iv = sigf(accA[0][j]);
                    const float fv = sigf(accA[1][j]);
                    const float gv = tanhfast(accA[2][j]);
                    const float ov = sigf(accA[3][j]);
                    const float c  = fv*cst[j] + iv*gv;
                    cst[j] = c;
                    const float h  = ov*tanhfast(c);
                    const unsigned short hb2 = f2bf(h);
                    s_h0hi[widx][lq*4+j][u] = (short)hb2;
                    s_h0lo[widx][lq*4+j][u] = (short)f2bf(h - bf2f(hb2));
                }
            }
            if (xth && (n+1) < TT) {                   // x(n+1) -> h0 buf[widx] k-slots 50-52
                const int tn = n + 1;
                const float xv = s_xs[(tn/TC)&1][xr][(tn%TC)*3 + xd];
                const unsigned short xh = f2bf(xv);
                s_h0hi[widx][xr][HD+xd] = (short)xh;
                s_h0lo[widx][xr][HD+xd] = (short)f2bf(xv - bf2f(xh));
            }
        } else {
            if (n >= 2 && n <= TT + 1) {               // pre1(n-2) = [h0(n-2)|h1(n-3)] @ W1
                const char* hb0 = (const char*)&s_h0hi[bidx][0][0];
                const char* lb0 = (const char*)&s_h0lo[bidx][0][0];
                bf16x8 ah[4], al[4];
                #pragma unroll
                for (int s = 0; s < 2; ++s) {
                    const int off = lr*(2*HS) + s*64 + lq*16;
                    ah[s]   = *(const bf16x8*)(hb0 + off);
                    al[s]   = *(const bf16x8*)(lb0 + off);
                    ah[2+s] = *(const bf16x8*)((const char*)&s_h1hi[0][0] + off);
                    al[2+s] = *(const bf16x8*)((const char*)&s_h1lo[0][0] + off);
                }
                #pragma unroll
                for (int tt = 0; tt < 4; ++tt) { const float b = bvT[tt]; accB[tt] = (f32x4){b,b,b,b}; }
                #pragma unroll
                for (int s = 0; s < 4; ++s) {
                    #pragma unroll
                    for (int tt = 0; tt < 4; ++tt)
                        accB[tt] = __builtin_amdgcn_mfma_f32_16x16x32_bf16(ah[s], bh[tt][s], accB[tt], 0,0,0);
                    #pragma unroll
                    for (int tt = 0; tt < 4; ++tt)
                        accB[tt] = __builtin_amdgcn_mfma_f32_16x16x32_bf16(al[s], bh[tt][s], accB[tt], 0,0,0);
                    #pragma unroll
                    for (int tt = 0; tt < 4; ++tt)
                        accB[tt] = __builtin_amdgcn_mfma_f32_16x16x32_bf16(ah[s], bl[tt][s], accB[tt], 0,0,0);
                }
            }
        }
        {
            const int t2s = n + 2;                     // stage next x chunk 2 ticks ahead
            if (t2s < TT && (t2s % TC) == 0) {
                const int cb = (t2s / TC) & 1;
                for (int p = tid; p < BRR*TC*3; p += 512) {
                    const int rr = p / (TC*3), q = p % (TC*3);
                    s_xs[cb][rr][q] = x[(size_t)(r0+rr)*(TT*3) + (size_t)t2s*3 + q];
                }
            }
        }
        __syncthreads();
    }

    // ---- FC epilogue: out = h1(TT-1) @ Wfc^T + bfc  (written at tick TT+2) ----
    if (tid < BRR*7) {
        const int r = tid / 7, o = tid % 7;
        float acc = bfc[o];
        #pragma unroll
        for (int uu = 0; uu < HD; ++uu)
            acc += (bf2f((unsigned short)s_h1hi[r][uu]) + bf2f((unsigned short)s_h1lo[r][uu])) * Wfc[o*HD + uu];
        out[(size_t)(r0+r)*7 + o] = acc;
    }
}

extern "C" void kernel_launch(void* const* d_in, const int* in_sizes, int n_in,
                              void* d_out, int out_size, void* d_ws, size_t ws_size,
                              hipStream_t stream) {
    const float* xp    = (const float*)d_in[0];
    const float* Wih0  = (const float*)d_in[1];
    const float* Whh0  = (const float*)d_in[2];
    const float* bih0  = (const float*)d_in[3];
    const float* bhh0  = (const float*)d_in[4];
    const float* Wih1  = (const float*)d_in[5];
    const float* Whh1  = (const float*)d_in[6];
    const float* bih1  = (const float*)d_in[7];
    const float* bhh1  = (const float*)d_in[8];
    const float* Wfc   = (const float*)d_in[9];
    const float* bfc   = (const float*)d_in[10];
    float* outp = (float*)d_out;

    const int B = in_sizes[0] / (TT * 3);   // 4096
    const int grid = B / BRR;               // 256 blocks, 1 per CU

    lstm2_mfma7<<<grid, 512, 0, stream>>>(
        xp, Wih0, Whh0, bih0, bhh0, Wih1, Whh1, bih1, bhh1, Wfc, bfc, outp);
}

// Round 11
// 443.689 us; speedup vs baseline: 1.5747x; 1.5747x over previous
//
#include <hip/hip_runtime.h>

#define HD 50
#define TT 512
#define BRR 16        // batch rows per block -> 256 blocks = 1/CU
#define TC 32         // x prefetch chunk (timesteps)
#define HS 72         // f16 slots per h row (144B stride; b128 A-reads bank-balanced)

using f16   = _Float16;
using f16x8 = __attribute__((ext_vector_type(8))) f16;
using f32x4 = __attribute__((ext_vector_type(4))) float;

__device__ __forceinline__ short f2h_bits(float f) {
    f16 h = (f16)f;                      // RNE
    return *reinterpret_cast<short*>(&h);
}
__device__ __forceinline__ float h2f(short b) {
    f16 h = *reinterpret_cast<f16*>(&b);
    return (float)h;
}
__device__ __forceinline__ float frcp(float x) { return __builtin_amdgcn_rcpf(x); }
__device__ __forceinline__ float sigf(float x) { return frcp(1.0f + __expf(-x)); }
__device__ __forceinline__ float tanhfast(float x) {
    return 1.0f - 2.0f * frcp(__expf(2.0f * x) + 1.0f);
}

// r8 structure (gate-major tiles, in-register EW, ONE barrier/tick) with
// single-term f16 MFMA replacing the bf16 hi/lo 3-term split:
//   MFMA/wave: A 24->8, B 48->16; h stored as plain f16 (no residual buffer).
// Waves 0-3: layer 0 (step n). Waves 4-7: layer 1 (step n-1).
// Wave w owns units u = 4*lr + (w&3); its 4 tiles = the 4 gate types of those
// units -> after MFMA, lane (lr,lq) holds acc[gate][j] for unit u, rows 4lq+j.
__global__ __launch_bounds__(512, 2) void lstm2_f16(
    const float* __restrict__ x,
    const float* __restrict__ Wih0, const float* __restrict__ Whh0,
    const float* __restrict__ bih0, const float* __restrict__ bhh0,
    const float* __restrict__ Wih1, const float* __restrict__ Whh1,
    const float* __restrict__ bih1, const float* __restrict__ bhh1,
    const float* __restrict__ Wfc, const float* __restrict__ bfc,
    float* __restrict__ out)
{
    __shared__ short s_h0[2][BRR][HS];   // k: 0-49 h0, 50-52 x, 53+ zero (f16 bits)
    __shared__ short s_h1[2][BRR][HS];   // k: 0-49 h1, 50+ zero
    __shared__ float s_xs[2][BRR][TC*3];

    const int tid  = threadIdx.x;
    const int wid  = tid >> 6;
    const int lane = tid & 63;
    const int lr   = lane & 15;    // B/D column = unit slot
    const int lq   = lane >> 4;    // k-octet / D row-quad
    const int r0   = blockIdx.x * BRR;
    const bool pathA = (wid < 4);
    const int  wsub  = wid & 3;
    const int  u     = lr * 4 + wsub;      // this lane's hidden unit
    const bool valid = (u < HD);

    // ---- weight B-fragments (f16), register-resident; tile tt = gate type ----
    f16x8 bw[4][4];
    float bvT[4];
    #pragma unroll
    for (int tt = 0; tt < 4; ++tt) {
        #pragma unroll
        for (int s = 0; s < 4; ++s) bw[tt][s] = (f16x8)0;
        const int g = tt * HD + (valid ? u : 0);     // gate-row in [0,200)
        if (pathA) {
            bvT[tt] = valid ? bih0[g] + bhh0[g] : 0.f;
            #pragma unroll
            for (int s = 0; s < 2; ++s) {
                #pragma unroll
                for (int j = 0; j < 8; ++j) {
                    const int k = s*32 + lq*8 + j;
                    float wv = 0.f;
                    if (valid) {
                        if (k < HD) wv = Whh0[g*HD + k];
                        else if (k < HD+3) wv = Wih0[g*3 + (k-HD)];
                    }
                    bw[tt][s][j] = (f16)wv;
                }
            }
        } else {
            bvT[tt] = valid ? bih1[g] + bhh1[g] : 0.f;
            #pragma unroll
            for (int s = 0; s < 4; ++s) {
                #pragma unroll
                for (int j = 0; j < 8; ++j) {
                    const int k = s*32 + lq*8 + j;   // 0-63: Wih1 k-space, 64-127: Whh1
                    float wv = 0.f;
                    if (valid) {
                        if (k < HD) wv = Wih1[g*HD + k];
                        else if (k >= 64 && k < 64+HD) wv = Whh1[g*HD + (k-64)];
                    }
                    bw[tt][s][j] = (f16)wv;
                }
            }
        }
    }

    // ---- per-lane c-state: 4 batch rows (4*lq+j) of unit u ----
    float cst[4] = {0.f, 0.f, 0.f, 0.f};

    // ---- x duty: tids 0-47 (subset of wave 0, pathA) ----
    const bool xth = (tid < 48);
    const int  xr  = tid / 3, xd = tid % 3;

    // ---- init LDS ----
    for (int p = tid; p < 2*BRR*HS; p += 512) {
        ((short*)s_h0)[p] = 0; ((short*)s_h1)[p] = 0;
    }
    for (int p = tid; p < BRR*TC*3; p += 512) {       // stage x chunk 0
        const int rr = p / (TC*3), q = p % (TC*3);
        s_xs[0][rr][q] = x[(size_t)(r0+rr)*(TT*3) + q];
    }
    __syncthreads();
    if (xth) {                                        // x(0) -> h0 buf 1 (read at tick 0)
        s_h0[1][xr][HD+xd] = f2h_bits(s_xs[0][xr][xd]);
    }
    __syncthreads();

    // ================= main loop: TT+1 ticks, ONE barrier each =================
    for (int n = 0; n <= TT; ++n) {
        if (pathA) {
            if (n < TT) {                              // pre0(n) = [h0(n-1)|x(n)] @ W0
                const char* hb0 = (const char*)&s_h0[(n+1)&1][0][0];
                f16x8 ah[2];
                #pragma unroll
                for (int s = 0; s < 2; ++s) {
                    const int off = lr*(2*HS) + s*64 + lq*16;
                    ah[s] = *(const f16x8*)(hb0 + off);
                }
                f32x4 acc[4];
                #pragma unroll
                for (int tt = 0; tt < 4; ++tt) { const float b = bvT[tt]; acc[tt] = (f32x4){b,b,b,b}; }
                #pragma unroll
                for (int s = 0; s < 2; ++s) {
                    #pragma unroll
                    for (int tt = 0; tt < 4; ++tt)
                        acc[tt] = __builtin_amdgcn_mfma_f32_16x16x32_f16(ah[s], bw[tt][s], acc[tt], 0,0,0);
                }
                if (valid) {                           // EW0 in-register -> h0(n) in buf[n&1]
                    #pragma unroll
                    for (int j = 0; j < 4; ++j) {
                        const float iv = sigf(acc[0][j]);
                        const float fv = sigf(acc[1][j]);
                        const float gv = tanhfast(acc[2][j]);
                        const float ov = sigf(acc[3][j]);
                        const float c  = fv*cst[j] + iv*gv;
                        cst[j] = c;
                        const float h  = ov*tanhfast(c);
                        s_h0[n&1][lq*4+j][u] = f2h_bits(h);
                    }
                }
            }
            if (xth && (n+1) < TT) {                   // x(n+1) -> h0 buf[n&1] k-slots 50-52
                const int tn = n + 1;
                s_h0[n&1][xr][HD+xd] = f2h_bits(s_xs[(tn/TC)&1][xr][(tn%TC)*3 + xd]);
            }
        } else {
            if (n >= 1) {                              // pre1(n-1) = [h0(n-1)|h1(n-2)] @ W1
                const char* hb0 = (const char*)&s_h0[(n+1)&1][0][0];
                const char* hb1 = (const char*)&s_h1[n&1][0][0];
                f16x8 ah[4];
                #pragma unroll
                for (int s = 0; s < 2; ++s) {
                    const int off = lr*(2*HS) + s*64 + lq*16;
                    ah[s]   = *(const f16x8*)(hb0 + off);
                    ah[2+s] = *(const f16x8*)(hb1 + off);
                }
                f32x4 acc[4];
                #pragma unroll
                for (int tt = 0; tt < 4; ++tt) { const float b = bvT[tt]; acc[tt] = (f32x4){b,b,b,b}; }
                #pragma unroll
                for (int s = 0; s < 4; ++s) {
                    #pragma unroll
                    for (int tt = 0; tt < 4; ++tt)
                        acc[tt] = __builtin_amdgcn_mfma_f32_16x16x32_f16(ah[s], bw[tt][s], acc[tt], 0,0,0);
                }
                if (valid) {                           // EW1 in-register -> h1(n-1) in buf[(n+1)&1]
                    #pragma unroll
                    for (int j = 0; j < 4; ++j) {
                        const float iv = sigf(acc[0][j]);
                        const float fv = sigf(acc[1][j]);
                        const float gv = tanhfast(acc[2][j]);
                        const float ov = sigf(acc[3][j]);
                        const float c  = fv*cst[j] + iv*gv;
                        cst[j] = c;
                        const float h  = ov*tanhfast(c);
                        s_h1[(n+1)&1][lq*4+j][u] = f2h_bits(h);
                    }
                }
            }
        }
        {
            const int t2s = n + 2;                     // stage next x chunk 2 ticks ahead
            if (t2s < TT && (t2s % TC) == 0) {
                const int cb = (t2s / TC) & 1;
                for (int p = tid; p < BRR*TC*3; p += 512) {
                    const int rr = p / (TC*3), q = p % (TC*3);
                    s_xs[cb][rr][q] = x[(size_t)(r0+rr)*(TT*3) + (size_t)t2s*3 + q];
                }
            }
        }
        __syncthreads();
    }

    // ---- FC epilogue: out = h1(TT-1) @ Wfc^T + bfc  (h1(511) in buf 1) ----
    if (tid < BRR*7) {
        const int r = tid / 7, o = tid % 7;
        float acc = bfc[o];
        #pragma unroll
        for (int uu = 0; uu < HD; ++uu)
            acc += h2f(s_h1[1][r][uu]) * Wfc[o*HD + uu];
        out[(size_t)(r0+r)*7 + o] = acc;
    }
}

extern "C" void kernel_launch(void* const* d_in, const int* in_sizes, int n_in,
                              void* d_out, int out_size, void* d_ws, size_t ws_size,
                              hipStream_t stream) {
    const float* xp    = (const float*)d_in[0];
    const float* Wih0  = (const float*)d_in[1];
    const float* Whh0  = (const float*)d_in[2];
    const float* bih0  = (const float*)d_in[3];
    const float* bhh0  = (const float*)d_in[4];
    const float* Wih1  = (const float*)d_in[5];
    const float* Whh1  = (const float*)d_in[6];
    const float* bih1  = (const float*)d_in[7];
    const float* bhh1  = (const float*)d_in[8];
    const float* Wfc   = (const float*)d_in[9];
    const float* bfc   = (const float*)d_in[10];
    float* outp = (float*)d_out;

    const int B = in_sizes[0] / (TT * 3);   // 4096
    const int grid = B / BRR;               // 256 blocks, 1 per CU

    lstm2_f16<<<grid, 512, 0, stream>>>(
        xp, Wih0, Whh0, bih0, bhh0, Wih1, Whh1, bih1, bhh1, Wfc, bfc, outp);
}

// Round 12
// 420.611 us; speedup vs baseline: 1.6611x; 1.0549x over previous
//
#include <hip/hip_runtime.h>

#define HD 50
#define TT 512
#define BRR 16        // batch rows per block -> 256 blocks = 1/CU
#define KS 136        // shorts per A row: 272B = 17*16B aligned; 68 dw = 4 mod 32 -> 2-way reads
// A-row k layout: [0..49]=h0(n-1), [50..52]=x(n), [53..63]=0, [64..113]=h1(n-2), [114..135]=0

using f16   = _Float16;
using f16x8 = __attribute__((ext_vector_type(8))) f16;
using f32x4 = __attribute__((ext_vector_type(4))) float;

#define LOG2E 1.4426950408889634f

__device__ __forceinline__ short f2h_bits(float f) {
    f16 h = (f16)f;                      // RNE
    return *reinterpret_cast<short*>(&h);
}
__device__ __forceinline__ float h2f(short b) {
    f16 h = *reinterpret_cast<f16*>(&b);
    return (float)h;
}
__device__ __forceinline__ float frcp(float x) { return __builtin_amdgcn_rcpf(x); }
#if __has_builtin(__builtin_amdgcn_exp2f)
__device__ __forceinline__ float fexp2(float x) { return __builtin_amdgcn_exp2f(x); }
#else
__device__ __forceinline__ float fexp2(float x) { return exp2f(x); }
#endif

// Unified symmetric schedule: every wave runs the SAME per-tick program.
// A(n) = [h0(n-1) | x(n) | h1(n-2)] (k=128); L0 weights zero over the h1 span,
// L1 weights zero over the x span -> one MFMA pass computes L0(n) and L1(n-1)
// gates together. Wave w owns (layer,unit) pairs p = 8*lr + w (p<50: L0 unit p;
// 50<=p<100: L1 unit p-50; p>=100 invalid -> x-duty lanes on waves 0-3).
// EW fully in-register (D: col=pair, row=4*lq+j); ONE barrier per tick;
// A double-buffered: tick n reads buf[n&1], all writes go to buf[(n+1)&1].
// exp2 folding: weights/bias pre-scaled by -log2e (i,f,o) / +2log2e (g).
__global__ __launch_bounds__(512, 2) void lstm2_uni(
    const float* __restrict__ x,
    const float* __restrict__ Wih0, const float* __restrict__ Whh0,
    const float* __restrict__ bih0, const float* __restrict__ bhh0,
    const float* __restrict__ Wih1, const float* __restrict__ Whh1,
    const float* __restrict__ bih1, const float* __restrict__ bhh1,
    const float* __restrict__ Wfc, const float* __restrict__ bfc,
    float* __restrict__ out)
{
    __shared__ short sA[2][BRR][KS];

    const int tid  = threadIdx.x;
    const int wid  = tid >> 6;
    const int lane = tid & 63;
    const int lr   = lane & 15;          // B/D column = pair slot
    const int lq   = lane >> 4;          // k-octet / D row-quad
    const int r0   = blockIdx.x * BRR;

    const int  p     = 8 * lr + wid;     // pair id 0..127
    const bool valid = (p < 100);
    const bool isL1  = valid && (p >= 50);
    const int  u     = valid ? (isL1 ? p - 50 : p) : 0;
    const int  wcol  = isL1 ? 64 + u : u;        // h write column in A

    // ---- weight B-fragments (f16, pre-scaled), register-resident ----
    f16x8 bw[4][4];
    float bvT[4];
    #pragma unroll
    for (int tt = 0; tt < 4; ++tt) {
        const float sc = (tt == 2) ? (2.0f * LOG2E) : (-LOG2E);
        const int g = tt * HD + u;       // layer-local gate row
        if (!isL1) {
            bvT[tt] = valid ? (bih0[g] + bhh0[g]) * sc : 0.f;
            #pragma unroll
            for (int s = 0; s < 4; ++s) {
                #pragma unroll
                for (int j = 0; j < 8; ++j) {
                    const int k = s*32 + lq*8 + j;
                    float wv = 0.f;
                    if (valid) {
                        if (k < HD) wv = Whh0[g*HD + k];
                        else if (k < HD + 3) wv = Wih0[g*3 + (k - HD)];
                    }
                    bw[tt][s][j] = (f16)(wv * sc);
                }
            }
        } else {
            bvT[tt] = (bih1[g] + bhh1[g]) * sc;
            #pragma unroll
            for (int s = 0; s < 4; ++s) {
                #pragma unroll
                for (int j = 0; j < 8; ++j) {
                    const int k = s*32 + lq*8 + j;
                    float wv = 0.f;
                    if (k < HD) wv = Wih1[g*HD + k];
                    else if (k >= 64 && k < 64 + HD) wv = Whh1[g*HD + (k - 64)];
                    bw[tt][s][j] = (f16)(wv * sc);
                }
            }
        }
    }

    // ---- per-lane c-state: 4 batch rows (4*lq+j) of this lane's (layer,unit) ----
    float cst[4] = {0.f, 0.f, 0.f, 0.f};

    // ---- x duty: the 48 invalid lanes of waves 0-3 (lr>=13 -> p>=104) ----
    const bool xduty = (wid < 4) && (lr >= 13);
    const int  xidx  = wid * 12 + (lr - 13) * 4 + lq;   // 0..47
    const int  xrow  = xidx / 3, xd = xidx % 3;

    // ---- init: zero both A buffers, then x(0) -> buf0 ----
    for (int q = tid; q < 2 * BRR * KS; q += 512) ((short*)sA)[q] = 0;
    __syncthreads();
    if (xduty) sA[0][xrow][HD + xd] = f2h_bits(x[(size_t)(r0 + xrow) * (TT*3) + xd]);
    __syncthreads();

    // ================= main loop: TT+1 ticks, ONE barrier each =================
    for (int n = 0; n <= TT; ++n) {
        // x(n+1) prefetch (global, L2-resident; consumed at end of tick)
        float xv = 0.f;
        const bool xact = xduty && (n + 1) < TT;
        if (xact) xv = x[(size_t)(r0 + xrow) * (TT*3) + (size_t)(n + 1) * 3 + xd];

        // ---- MFMA: gates for L0(n) and L1(n-1) in one pass ----
        const char* ab = (const char*)&sA[n & 1][0][0];
        f16x8 a[4];
        #pragma unroll
        for (int s = 0; s < 4; ++s)
            a[s] = *(const f16x8*)(ab + lr * (2 * KS) + s * 64 + lq * 16);
        f32x4 acc[4];
        #pragma unroll
        for (int tt = 0; tt < 4; ++tt) { const float b = bvT[tt]; acc[tt] = (f32x4){b, b, b, b}; }
        #pragma unroll
        for (int s = 0; s < 4; ++s) {
            #pragma unroll
            for (int tt = 0; tt < 4; ++tt)
                acc[tt] = __builtin_amdgcn_mfma_f32_16x16x32_f16(a[s], bw[tt][s], acc[tt], 0, 0, 0);
        }

        // ---- EW in-register -> h into buf[(n+1)&1] ----
        const bool act = valid && (isL1 ? (n >= 1) : (n < TT));
        if (act) {
            #pragma unroll
            for (int j = 0; j < 4; ++j) {
                const float iv = frcp(1.0f + fexp2(acc[0][j]));
                const float fv = frcp(1.0f + fexp2(acc[1][j]));
                const float gv = 1.0f - 2.0f * frcp(1.0f + fexp2(acc[2][j]));
                const float ov = frcp(1.0f + fexp2(acc[3][j]));
                const float c  = fv * cst[j] + iv * gv;
                cst[j] = c;
                const float th = 1.0f - 2.0f * frcp(1.0f + fexp2(c * (2.0f * LOG2E)));
                const float h  = ov * th;
                sA[(n + 1) & 1][lq * 4 + j][wcol] = f2h_bits(h);
            }
        }
        if (xact) sA[(n + 1) & 1][xrow][HD + xd] = f2h_bits(xv);
        __syncthreads();
    }

    // ---- FC epilogue: h1(TT-1) sits in buf[(TT+1)&1] = buf[1], cols 64..113 ----
    if (tid < BRR * 7) {
        const int r = tid / 7, o = tid % 7;
        float acc = bfc[o];
        #pragma unroll
        for (int uu = 0; uu < HD; ++uu)
            acc += h2f(sA[1][r][64 + uu]) * Wfc[o * HD + uu];
        out[(size_t)(r0 + r) * 7 + o] = acc;
    }
}

extern "C" void kernel_launch(void* const* d_in, const int* in_sizes, int n_in,
                              void* d_out, int out_size, void* d_ws, size_t ws_size,
                              hipStream_t stream) {
    const float* xp    = (const float*)d_in[0];
    const float* Wih0  = (const float*)d_in[1];
    const float* Whh0  = (const float*)d_in[2];
    const float* bih0  = (const float*)d_in[3];
    const float* bhh0  = (const float*)d_in[4];
    const float* Wih1  = (const float*)d_in[5];
    const float* Whh1  = (const float*)d_in[6];
    const float* bih1  = (const float*)d_in[7];
    const float* bhh1  = (const float*)d_in[8];
    const float* Wfc   = (const float*)d_in[9];
    const float* bfc   = (const float*)d_in[10];
    float* outp = (float*)d_out;

    const int B = in_sizes[0] / (TT * 3);   // 4096
    const int grid = B / BRR;               // 256 blocks, 1 per CU

    lstm2_uni<<<grid, 512, 0, stream>>>(
        xp, Wih0, Whh0, bih0, bhh0, Wih1, Whh1, bih1, bhh1, Wfc, bfc, outp);
}

// Round 13
// 399.098 us; speedup vs baseline: 1.7506x; 1.0539x over previous
//
#include <hip/hip_runtime.h>

#define HD 50
#define TT 512
#define BRR 16        // batch rows per block -> 256 blocks = 1/CU
#define TC 32         // x prefetch chunk (timesteps)
#define KS 136        // shorts per A row: 272B = 17*16B aligned; 68 dw = 4 mod 32 -> 2-way reads
// A-row k layout: [0..49]=h0(n-1), [50..52]=x(n), [53..63]=0, [64..113]=h1(n-2), [114..135]=0

using f16   = _Float16;
using f16x8 = __attribute__((ext_vector_type(8))) f16;
using f32x4 = __attribute__((ext_vector_type(4))) float;

#define LOG2E 1.4426950408889634f

__device__ __forceinline__ short f2h_bits(float f) {
    f16 h = (f16)f;                      // RNE
    return *reinterpret_cast<short*>(&h);
}
__device__ __forceinline__ float h2f(short b) {
    f16 h = *reinterpret_cast<f16*>(&b);
    return (float)h;
}
__device__ __forceinline__ float frcp(float x) { return __builtin_amdgcn_rcpf(x); }
#if __has_builtin(__builtin_amdgcn_exp2f)
__device__ __forceinline__ float fexp2(float x) { return __builtin_amdgcn_exp2f(x); }
#else
__device__ __forceinline__ float fexp2(float x) { return exp2f(x); }
#endif

// Unified symmetric schedule (r12 champion) + LDS x-staging + fused-rcp EW.
// A(n) = [h0(n-1) | x(n) | h1(n-2)] (k=128); one MFMA pass computes L0(n) and
// L1(n-1) gates. Wave w owns (layer,unit) pairs p = 8*lr + w. EW in-register;
// ONE barrier/tick; A double-buffered. Weights pre-scaled by -log2e / +2log2e.
// EW uses fused denominators: 5 exp2 + 3 rcp per unit-row (was 5+5).
__global__ __launch_bounds__(512, 2) void lstm2_uni2(
    const float* __restrict__ x,
    const float* __restrict__ Wih0, const float* __restrict__ Whh0,
    const float* __restrict__ bih0, const float* __restrict__ bhh0,
    const float* __restrict__ Wih1, const float* __restrict__ Whh1,
    const float* __restrict__ bih1, const float* __restrict__ bhh1,
    const float* __restrict__ Wfc, const float* __restrict__ bfc,
    float* __restrict__ out)
{
    __shared__ short s_A[2][BRR][KS];
    __shared__ float s_xs[2][BRR][TC * 3];

    const int tid  = threadIdx.x;
    const int wid  = tid >> 6;
    const int lane = tid & 63;
    const int lr   = lane & 15;          // B/D column = pair slot
    const int lq   = lane >> 4;          // k-octet / D row-quad
    const int r0   = blockIdx.x * BRR;

    const int  p     = 8 * lr + wid;     // pair id 0..127
    const bool valid = (p < 100);
    const bool isL1  = valid && (p >= 50);
    const int  u     = valid ? (isL1 ? p - 50 : p) : 0;
    const int  wcol  = isL1 ? 64 + u : u;        // h write column in A

    // ---- weight B-fragments (f16, pre-scaled), register-resident ----
    f16x8 bw[4][4];
    float bvT[4];
    #pragma unroll
    for (int tt = 0; tt < 4; ++tt) {
        const float sc = (tt == 2) ? (2.0f * LOG2E) : (-LOG2E);
        const int g = tt * HD + u;       // layer-local gate row
        if (!isL1) {
            bvT[tt] = valid ? (bih0[g] + bhh0[g]) * sc : 0.f;
            #pragma unroll
            for (int s = 0; s < 4; ++s) {
                #pragma unroll
                for (int j = 0; j < 8; ++j) {
                    const int k = s*32 + lq*8 + j;
                    float wv = 0.f;
                    if (valid) {
                        if (k < HD) wv = Whh0[g*HD + k];
                        else if (k < HD + 3) wv = Wih0[g*3 + (k - HD)];
                    }
                    bw[tt][s][j] = (f16)(wv * sc);
                }
            }
        } else {
            bvT[tt] = (bih1[g] + bhh1[g]) * sc;
            #pragma unroll
            for (int s = 0; s < 4; ++s) {
                #pragma unroll
                for (int j = 0; j < 8; ++j) {
                    const int k = s*32 + lq*8 + j;
                    float wv = 0.f;
                    if (k < HD) wv = Wih1[g*HD + k];
                    else if (k >= 64 && k < 64 + HD) wv = Whh1[g*HD + (k - 64)];
                    bw[tt][s][j] = (f16)(wv * sc);
                }
            }
        }
    }

    // ---- per-lane c-state: 4 batch rows (4*lq+j) of this lane's (layer,unit) ----
    float cst[4] = {0.f, 0.f, 0.f, 0.f};

    // ---- x duty: the 48 invalid lanes of waves 0-3 (lr>=13 -> p>=104) ----
    const bool xduty = (wid < 4) && (lr >= 13);
    const int  xidx  = wid * 12 + (lr - 13) * 4 + lq;   // 0..47
    const int  xrow  = xidx / 3, xd = xidx % 3;

    // ---- init: zero A buffers, stage x chunk 0, write x(0) ----
    for (int q = tid; q < 2 * BRR * KS; q += 512) ((short*)s_A)[q] = 0;
    for (int q = tid; q < BRR * TC * 3; q += 512) {
        const int rr = q / (TC * 3), qq = q % (TC * 3);
        s_xs[0][rr][qq] = x[(size_t)(r0 + rr) * (TT * 3) + qq];
    }
    __syncthreads();
    if (xduty) s_A[0][xrow][HD + xd] = f2h_bits(s_xs[0][xrow][xd]);
    __syncthreads();

    // ================= main loop: TT+1 ticks, ONE barrier each =================
    for (int n = 0; n <= TT; ++n) {
        // ---- MFMA: gates for L0(n) and L1(n-1) in one pass ----
        const char* ab = (const char*)&s_A[n & 1][0][0];
        f16x8 a[4];
        #pragma unroll
        for (int s = 0; s < 4; ++s)
            a[s] = *(const f16x8*)(ab + lr * (2 * KS) + s * 64 + lq * 16);
        f32x4 acc[4];
        #pragma unroll
        for (int tt = 0; tt < 4; ++tt) { const float b = bvT[tt]; acc[tt] = (f32x4){b, b, b, b}; }
        #pragma unroll
        for (int s = 0; s < 4; ++s) {
            #pragma unroll
            for (int tt = 0; tt < 4; ++tt)
                acc[tt] = __builtin_amdgcn_mfma_f32_16x16x32_f16(a[s], bw[tt][s], acc[tt], 0, 0, 0);
        }

        // ---- EW in-register (fused rcp) -> h into buf[(n+1)&1] ----
        const bool act = valid && (isL1 ? (n >= 1) : (n < TT));
        if (act) {
            #pragma unroll
            for (int j = 0; j < 4; ++j) {
                const float ei = fexp2(acc[0][j]);
                const float ef = fexp2(acc[1][j]);
                const float eg = fexp2(acc[2][j]);
                const float eo = fexp2(acc[3][j]);
                const float ig = (eg - 1.0f) * frcp((eg + 1.0f) * (1.0f + ei));
                const float fv = frcp(1.0f + ef);
                const float c  = fv * cst[j] + ig;
                cst[j] = c;
                const float ec = fexp2(c * (2.0f * LOG2E));
                const float h  = (ec - 1.0f) * frcp((ec + 1.0f) * (1.0f + eo));
                s_A[(n + 1) & 1][lq * 4 + j][wcol] = f2h_bits(h);
            }
        }
        if (xduty && (n + 1) < TT) {                  // x(n+1) from staged LDS
            const int tn = n + 1;
            s_A[(n + 1) & 1][xrow][HD + xd] =
                f2h_bits(s_xs[(tn / TC) & 1][xrow][(tn % TC) * 3 + xd]);
        }
        {
            const int t2s = n + 2;                    // stage next x chunk 2 ticks ahead
            if (t2s < TT && (t2s % TC) == 0) {
                const int cb = (t2s / TC) & 1;
                for (int q = tid; q < BRR * TC * 3; q += 512) {
                    const int rr = q / (TC * 3), qq = q % (TC * 3);
                    s_xs[cb][rr][qq] = x[(size_t)(r0 + rr) * (TT * 3) + (size_t)t2s * 3 + qq];
                }
            }
        }
        __syncthreads();
    }

    // ---- FC epilogue: h1(TT-1) sits in buf[(TT+1)&1] = buf[1], cols 64..113 ----
    if (tid < BRR * 7) {
        const int r = tid / 7, o = tid % 7;
        float acc = bfc[o];
        #pragma unroll
        for (int uu = 0; uu < HD; ++uu)
            acc += h2f(s_A[1][r][64 + uu]) * Wfc[o * HD + uu];
        out[(size_t)(r0 + r) * 7 + o] = acc;
    }
}

extern "C" void kernel_launch(void* const* d_in, const int* in_sizes, int n_in,
                              void* d_out, int out_size, void* d_ws, size_t ws_size,
                              hipStream_t stream) {
    const float* xp    = (const float*)d_in[0];
    const float* Wih0  = (const float*)d_in[1];
    const float* Whh0  = (const float*)d_in[2];
    const float* bih0  = (const float*)d_in[3];
    const float* bhh0  = (const float*)d_in[4];
    const float* Wih1  = (const float*)d_in[5];
    const float* Whh1  = (const float*)d_in[6];
    const float* bih1  = (const float*)d_in[7];
    const float* bhh1  = (const float*)d_in[8];
    const float* Wfc   = (const float*)d_in[9];
    const float* bfc   = (const float*)d_in[10];
    float* outp = (float*)d_out;

    const int B = in_sizes[0] / (TT * 3);   // 4096
    const int grid = B / BRR;               // 256 blocks, 1 per CU

    lstm2_uni2<<<grid, 512, 0, stream>>>(
        xp, Wih0, Whh0, bih0, bhh0, Wih1, Whh1, bih1, bhh1, Wfc, bfc, outp);
}